// Round 6
// baseline (300.086 us; speedup 1.0000x reference)
//
#include <hip/hip_runtime.h>
#include <cmath>

#define DD   10
#define FF   32
#define OUTN 32
#define PPW  6           // pairs per 64-lane wave (lanes 0..59 active, 60..63 shadow)
#define NW   4           // waves per block
#define NT   (NW * 64)

typedef float f32x4 __attribute__((ext_vector_type(4)));

// Kernel 1: summed[b,v,f] = sum_d inputs[b,v,d,f]  (f32x4, nt loads) — at roofline
__global__ __launch_bounds__(256) void sum_d4_kernel(
    const f32x4* __restrict__ in, f32x4* __restrict__ out, int n4) {
    int idx = blockIdx.x * 256 + threadIdx.x;
    if (idx >= n4) return;
    int f4 = idx & 7;
    int bv = idx >> 3;
    const f32x4* p = in + (size_t)bv * (DD * 8) + f4;
    f32x4 s = __builtin_nontemporal_load(p);
#pragma unroll
    for (int d = 1; d < DD; ++d) s += __builtin_nontemporal_load(p + d * 8);
    out[idx] = s;   // re-read by gat: keep cacheable
}

// Kernel 2: one ROW (pair,direction) per lane. No LDS dense; W via s_load.
__global__ __launch_bounds__(NT) void gat_kernel(
    const float* __restrict__ summed,
    const float* __restrict__ init,
    const float* __restrict__ mask,
    const float* __restrict__ Wk,
    const float* __restrict__ Wb,
    const float* __restrict__ Ak,
    const int* __restrict__ adj,
    const int* __restrict__ mask_index_p,
    float* __restrict__ out,
    int B, int V) {
    const int t    = threadIdx.x;
    const int lane = t & 63;
    const int w    = t >> 6;

    int p = lane / 10;                       // pair slot 0..6
    int r = lane - p * 10;                   // direction 0..9
    const bool lane_ok = p < PPW;
    const int  pe = lane_ok ? p : PPW - 1;   // shadow lanes duplicate pair 5

    const int BV = B * V;
    const int pair0 = (blockIdx.x * NW + w) * PPW;
    int bv = pair0 + pe;
    const bool valid = lane_ok && (bv < BV);
    if (bv >= BV) bv = BV - 1;
    // b = bv / V with B==4: two nested selects (no int div)
    const int b = (bv >= 2 * V) ? ((bv >= 3 * V) ? 3 : 2) : ((bv >= V) ? 1 : 0);

    const int mask_index = *mask_index_p;
    const int row = bv * DD + r;             // global row id, lane-contiguous

    const int   a  = adj[row];               // coalesced dword
    const float zm = 1.f - mask[row];        // coalesced dword
    int ac = a < 0 ? 0 : (a >= V ? V - 1 : a);            // JAX clamp semantics
    const float szg = (a == mask_index) ? 0.f : zm;

    // ---- full gi row in registers: 8 gather b128 + 8 init b128 (per lane) ----
    const f32x4* gp = (const f32x4*)(summed + ((size_t)b * V + (size_t)ac) * FF);
    const f32x4* ip = (const f32x4*)(init + (size_t)row * FF);
    f32x4 gi[8];
#pragma unroll
    for (int q = 0; q < 8; ++q) {
        f32x4 gv = gp[q];                                 // L2-resident gather
        f32x4 iv = __builtin_nontemporal_load(ip + q);    // streamed
        gi[q] = szg * gv + zm * iv;
    }

    // ---- dense F->OUT: W rows at uniform addresses -> s_load (SMEM pipe) ----
    float T[OUTN];
#pragma unroll
    for (int o = 0; o < OUTN; ++o) T[o] = Wb[o];          // uniform -> s_load
#pragma unroll
    for (int f = 0; f < FF; ++f) {
        const float gf = gi[f >> 2][f & 3];
        const float* wrow = Wk + f * OUTN;                // uniform row base
#pragma unroll
        for (int o = 0; o < OUTN; ++o)
            T[o] = fmaf(gf, wrow[o], T[o]);               // v_fmac with SGPR src
    }

    // ---- relu * zm, then in-lane attn dot (4 split chains) ----
    float a0 = 0.f, a1 = 0.f, a2 = 0.f, a3 = 0.f;
#pragma unroll
    for (int o = 0; o < OUTN; o += 4) {
        T[o + 0] = fmaxf(T[o + 0], 0.f) * zm;
        T[o + 1] = fmaxf(T[o + 1], 0.f) * zm;
        T[o + 2] = fmaxf(T[o + 2], 0.f) * zm;
        T[o + 3] = fmaxf(T[o + 3], 0.f) * zm;
        a0 = fmaf(T[o + 0], Ak[o + 0], a0);               // Ak uniform -> s_load
        a1 = fmaf(T[o + 1], Ak[o + 1], a1);
        a2 = fmaf(T[o + 2], Ak[o + 2], a2);
        a3 = fmaf(T[o + 3], Ak[o + 3], a3);
    }
    const float aw = (a0 + a1) + (a2 + a3) - 1e7f * (1.f - zm);

    // ---- softmax over the pair's 10 lanes via ds_bpermute ----
    const int base = pe * 10 * 4;
    float vals[DD];
    float mx = -INFINITY;
#pragma unroll
    for (int d = 0; d < DD; ++d) {
        vals[d] = __int_as_float(
            __builtin_amdgcn_ds_bpermute(base + 4 * d, __float_as_int(aw)));
        mx = fmaxf(mx, vals[d]);
    }
    float den = 0.f;
#pragma unroll
    for (int d = 0; d < DD; ++d) den += __expf(vals[d] - mx);
    const float coef = __expf(aw - mx) / den;

    // ---- out row = coef * T, 8 nt b128 stores (lane-contiguous rows) ----
    if (valid) {
        f32x4* op = (f32x4*)(out + (size_t)row * FF);
#pragma unroll
        for (int q = 0; q < 8; ++q) {
            f32x4 vv;
            vv.x = coef * T[4 * q + 0];
            vv.y = coef * T[4 * q + 1];
            vv.z = coef * T[4 * q + 2];
            vv.w = coef * T[4 * q + 3];
            __builtin_nontemporal_store(vv, op + q);
        }
    }
}

extern "C" void kernel_launch(void* const* d_in, const int* in_sizes, int n_in,
                              void* d_out, int out_size, void* d_ws, size_t ws_size,
                              hipStream_t stream) {
    const float* inputs = (const float*)d_in[0];
    const float* init   = (const float*)d_in[1];
    const float* mask   = (const float*)d_in[2];
    const float* Wk     = (const float*)d_in[3];
    const float* Wb     = (const float*)d_in[4];
    const float* Ak     = (const float*)d_in[5];
    const int*   adj    = (const int*)d_in[6];
    const int*   mip    = (const int*)d_in[7];

    const int B   = 4;
    const int BVD = in_sizes[2];          // B*V*D
    const int V   = BVD / (B * DD);
    const int BV  = B * V;

    float* summed = (float*)d_ws;         // B*V*FF floats = 10.24 MB
    int n4 = BV * (FF / 4);
    hipLaunchKernelGGL(sum_d4_kernel, dim3((n4 + 255) / 256), dim3(256), 0, stream,
                       (const f32x4*)inputs, (f32x4*)summed, n4);
    const int ppb = NW * PPW;             // 24 pairs per block
    hipLaunchKernelGGL(gat_kernel, dim3((BV + ppb - 1) / ppb), dim3(NT), 0, stream,
                       summed, init, mask, Wk, Wb, Ak, adj, mip, (float*)d_out, B, V);
}

// Round 7
// 81.608 us; speedup vs baseline: 3.6772x; 3.6772x over previous
//
#include <hip/hip_runtime.h>
#include <cmath>

#define DD     10
#define FF     32
#define OUTN   32
#define PPW    6                 // pairs per wave (60 rows, lanes 60-63 shadow)
#define NW     4                 // waves per block
#define NT     (NW * 64)
#define RPW    (PPW * DD)        // 60 rows per wave
#define STRIDE 36                // LDS row stride in floats (144 B, 16B-aligned)

typedef float f32x4 __attribute__((ext_vector_type(4)));
typedef float f32x2 __attribute__((ext_vector_type(2)));

// Kernel 1: summed[b,v,f] = sum_d inputs[b,v,d,f]  — at its roofline
__global__ __launch_bounds__(256) void sum_d4_kernel(
    const f32x4* __restrict__ in, f32x4* __restrict__ out, int n4) {
    int idx = blockIdx.x * 256 + threadIdx.x;
    if (idx >= n4) return;
    int f4 = idx & 7;
    int bv = idx >> 3;
    const f32x4* p = in + (size_t)bv * (DD * 8) + f4;
    f32x4 s = __builtin_nontemporal_load(p);
#pragma unroll
    for (int d = 1; d < DD; ++d) s += __builtin_nontemporal_load(p + d * 8);
    out[idx] = s;
}

// Kernel 2: coalesced staging (lane=f) -> LDS transpose -> per-lane-row dense.
__global__ __launch_bounds__(NT) void gat_kernel(
    const float* __restrict__ summed,
    const float* __restrict__ init,
    const float* __restrict__ mask,
    const float* __restrict__ Wk,
    const float* __restrict__ Wb,
    const float* __restrict__ Ak,
    const int* __restrict__ adj,
    const int* __restrict__ mask_index_p,
    float* __restrict__ out,
    int B, int V) {
    __shared__ float sROW[NW][RPW][STRIDE];   // 34560 B

    const int t    = threadIdx.x;
    const int lane = t & 63;
    const int w    = t >> 6;
    const int f    = lane & 31;
    const int hi   = lane >> 5;
    const int BV   = B * V;
    const int NR   = BV * DD;
    const int mask_index = *mask_index_p;

    const int wave_pair0 = (blockIdx.x * NW + w) * PPW;
    const int wave_row0  = wave_pair0 * DD;
    const bool full = (wave_pair0 + PPW) <= BV;

    // ---- per-slot prep (lane = slot): packed gather descriptor + zm ----
    int slot_row = wave_row0 + lane;
    if (slot_row >= NR) slot_row = NR - 1;
    const int   a_s  = adj[slot_row];
    const float zm_s = 1.f - mask[slot_row];
    int ac = a_s < 0 ? 0 : (a_s >= V ? V - 1 : a_s);          // JAX clamp
    int bv_s = slot_row / DD;
    int b_s  = (bv_s >= 2 * V) ? ((bv_s >= 3 * V) ? 3 : 2) : ((bv_s >= V) ? 1 : 0);
    const int gidx = ((b_s * V + ac) << 7) | ((a_s == mask_index) ? 1 : 0);

    // ---- stage 1: build raw rows (gather + init) in LDS, coalesced ----
    const int vhi4 = hi << 2;
    float* wbase = &sROW[w][0][0];
    float* wptr  = wbase + hi * STRIDE + f;       // + i*2*STRIDE per iter (imm)
    const char* sum_bytes = (const char*)summed;

    if (full) {
        const float* ip = init + (size_t)wave_row0 * FF + lane;   // linear!
#pragma unroll
        for (int i = 0; i < RPW / 2; ++i) {
            int gp  = __builtin_amdgcn_ds_bpermute((i << 3) + vhi4, gidx);
            int off = (gp & ~127) + (f << 2);
            float g = *(const float*)(sum_bytes + off);
            g = (gp & 1) ? 0.f : g;
            float iv = __builtin_nontemporal_load(ip + i * 64);
            wptr[i * (2 * STRIDE)] = g + iv;
        }
    } else {
#pragma unroll
        for (int i = 0; i < RPW / 2; ++i) {
            int gp  = __builtin_amdgcn_ds_bpermute((i << 3) + vhi4, gidx);
            int off = (gp & ~127) + (f << 2);
            float g = *(const float*)(sum_bytes + off);
            g = (gp & 1) ? 0.f : g;
            int rr = wave_row0 + 2 * i + hi;
            if (rr >= NR) rr = NR - 1;
            float iv = init[(size_t)rr * FF + f];
            wptr[i * (2 * STRIDE)] = g + iv;
        }
    }

    // ---- stage 2: per-lane own row ----
    int p_raw = lane / DD;                     // 0..6
    int r_own = lane - p_raw * DD;
    const int pe   = (p_raw < PPW) ? p_raw : (PPW - 1);
    const int slot = pe * DD + r_own;          // <= 59
    float* rowp = &sROW[w][slot][0];

    f32x4 gi4[8];
#pragma unroll
    for (int q = 0; q < 8; ++q) gi4[q] = *(const f32x4*)(rowp + 4 * q);

    // zm of own row (lane<60: identity; shadows: fetch from slot lane)
    const float zm_o = __int_as_float(
        __builtin_amdgcn_ds_bpermute(slot << 2, __float_as_int(zm_s)));

    // dense: dot = raw @ W (W/bias/a uniform -> s_load; f32x2 -> v_pk_fma_f32)
    const f32x2* W2 = (const f32x2*)Wk;
    const f32x2* b2 = (const f32x2*)Wb;
    const f32x2* A2 = (const f32x2*)Ak;
    f32x2 T2[16];
#pragma unroll
    for (int i = 0; i < 16; ++i) T2[i] = (f32x2){0.f, 0.f};
#pragma unroll
    for (int ff = 0; ff < FF; ++ff) {
        float gf = gi4[ff >> 2][ff & 3];
        f32x2 gf2 = {gf, gf};
#pragma unroll
        for (int i = 0; i < 16; ++i) T2[i] = gf2 * W2[ff * 16 + i] + T2[i];
    }
    // T = relu(zm*dot + bias) * zm ; attn dot in-lane
    f32x2 z2 = {zm_o, zm_o};
    f32x2 acc2 = {0.f, 0.f};
#pragma unroll
    for (int i = 0; i < 16; ++i) {
        f32x2 v = z2 * T2[i] + b2[i];
        v.x = fmaxf(v.x, 0.f);
        v.y = fmaxf(v.y, 0.f);
        v = v * z2;
        T2[i] = v;
        acc2 = v * A2[i] + acc2;
    }
    const float aw = acc2.x + acc2.y - 1e7f * (1.f - zm_o);

    // softmax over the pair's 10 rows via ds_bpermute
    const int pe40 = pe * 40;
    float vals[DD];
    float mx = -INFINITY;
#pragma unroll
    for (int d = 0; d < DD; ++d) {
        vals[d] = __int_as_float(
            __builtin_amdgcn_ds_bpermute(pe40 + 4 * d, __float_as_int(aw)));
        mx = fmaxf(mx, vals[d]);
    }
    float den = 0.f;
#pragma unroll
    for (int d = 0; d < DD; ++d) den += __expf(vals[d] - mx);
    const float coef = __expf(aw - mx) / den;

    // writeback coef*T to own LDS row (guard: shadows would duplicate slots)
    if (p_raw < PPW) {
        f32x2 c2 = {coef, coef};
#pragma unroll
        for (int q = 0; q < 8; ++q) {
            f32x2 lo = T2[2 * q] * c2;
            f32x2 hv = T2[2 * q + 1] * c2;
            f32x4 vv;
            vv.x = lo.x; vv.y = lo.y; vv.z = hv.x; vv.w = hv.y;
            *(f32x4*)(rowp + 4 * q) = vv;
        }
    }

    // ---- epilogue: coalesced nt b128 stores ----
    int lim4;
    if (full) lim4 = RPW * 8;
    else {
        int nrows = NR - wave_row0;
        if (nrows < 0) nrows = 0;
        if (nrows > RPW) nrows = RPW;
        lim4 = nrows * 8;
    }
    f32x4* ob = (f32x4*)(out + (size_t)wave_row0 * FF);
#pragma unroll
    for (int k = 0; k < 8; ++k) {
        int m = lane + (k << 6);
        if (m < lim4) {
            const f32x4 v = *(const f32x4*)(wbase + (m >> 3) * STRIDE + ((m & 7) << 2));
            __builtin_nontemporal_store(v, ob + m);
        }
    }
}

extern "C" void kernel_launch(void* const* d_in, const int* in_sizes, int n_in,
                              void* d_out, int out_size, void* d_ws, size_t ws_size,
                              hipStream_t stream) {
    const float* inputs = (const float*)d_in[0];
    const float* init   = (const float*)d_in[1];
    const float* mask   = (const float*)d_in[2];
    const float* Wk     = (const float*)d_in[3];
    const float* Wb     = (const float*)d_in[4];
    const float* Ak     = (const float*)d_in[5];
    const int*   adj    = (const int*)d_in[6];
    const int*   mip    = (const int*)d_in[7];

    const int B   = 4;
    const int BVD = in_sizes[2];          // B*V*D
    const int V   = BVD / (B * DD);
    const int BV  = B * V;

    float* summed = (float*)d_ws;         // B*V*FF floats = 10.24 MB
    int n4 = BV * (FF / 4);
    hipLaunchKernelGGL(sum_d4_kernel, dim3((n4 + 255) / 256), dim3(256), 0, stream,
                       (const f32x4*)inputs, (f32x4*)summed, n4);
    const int ppb = NW * PPW;             // 24 pairs per block
    hipLaunchKernelGGL(gat_kernel, dim3((BV + ppb - 1) / ppb), dim3(NT), 0, stream,
                       summed, init, mask, Wk, Wb, Ak, adj, mip, (float*)d_out, B, V);
}

// Round 8
// 79.772 us; speedup vs baseline: 3.7618x; 1.0230x over previous
//
#include <hip/hip_runtime.h>
#include <cmath>

#define DD     10
#define FF     32
#define OUTN   32
#define PPW    6                 // pairs per wave (60 rows, lanes 60-63 shadow)
#define NW     2                 // waves per block (smaller LDS -> more blocks/CU)
#define NT     (NW * 64)
#define RPW    (PPW * DD)        // 60 rows per wave
#define STRIDE 36                // LDS row stride in floats (144 B, 16B-aligned)

typedef float f32x4 __attribute__((ext_vector_type(4)));
typedef float f32x2 __attribute__((ext_vector_type(2)));

// Kernel 1: summed[b,v,f] = sum_d inputs[b,v,d,f]  — at its roofline
__global__ __launch_bounds__(256) void sum_d4_kernel(
    const f32x4* __restrict__ in, f32x4* __restrict__ out, int n4) {
    int idx = blockIdx.x * 256 + threadIdx.x;
    if (idx >= n4) return;
    int f4 = idx & 7;
    int bv = idx >> 3;
    const f32x4* p = in + (size_t)bv * (DD * 8) + f4;
    f32x4 s = __builtin_nontemporal_load(p);
#pragma unroll
    for (int d = 1; d < DD; ++d) s += __builtin_nontemporal_load(p + d * 8);
    out[idx] = s;
}

// Kernel 2: coalesced staging (lane=f) -> LDS transpose -> per-lane-row dense.
__global__ __launch_bounds__(NT) void gat_kernel(
    const float* __restrict__ summed,
    const float* __restrict__ init,
    const float* __restrict__ mask,
    const float* __restrict__ Wk,
    const float* __restrict__ Wb,
    const float* __restrict__ Ak,
    const int* __restrict__ adj,
    const int* __restrict__ mask_index_p,
    float* __restrict__ out,
    int B, int V) {
    __shared__ float sROW[NW][RPW][STRIDE];   // 17280 B -> ~9 blocks/CU

    const int t    = threadIdx.x;
    const int lane = t & 63;
    const int w    = t >> 6;
    const int f    = lane & 31;
    const int hi   = lane >> 5;
    const int BV   = B * V;
    const int NR   = BV * DD;
    const int mask_index = *mask_index_p;

    const int wave_pair0 = (blockIdx.x * NW + w) * PPW;
    const int wave_row0  = wave_pair0 * DD;
    const bool full = (wave_pair0 + PPW) <= BV;

    // ---- per-slot prep (lane = slot): packed gather descriptor + zm ----
    int slot_row = wave_row0 + lane;
    if (slot_row >= NR) slot_row = NR - 1;
    const int   a_s  = adj[slot_row];
    const float zm_s = 1.f - mask[slot_row];
    int ac = a_s < 0 ? 0 : (a_s >= V ? V - 1 : a_s);          // JAX clamp
    int bv_s = slot_row / DD;
    int b_s  = (bv_s >= 2 * V) ? ((bv_s >= 3 * V) ? 3 : 2) : ((bv_s >= V) ? 1 : 0);
    const int gidx = ((b_s * V + ac) << 7) | ((a_s == mask_index) ? 1 : 0);

    // ---- stage 1: build raw rows (gather + init) in LDS, coalesced ----
    const int vhi4 = hi << 2;
    float* wbase = &sROW[w][0][0];
    float* wptr  = wbase + hi * STRIDE + f;       // + i*2*STRIDE per iter (imm)
    const char* sum_bytes = (const char*)summed;

    if (full) {
        const float* ip = init + (size_t)wave_row0 * FF + lane;   // linear!
#pragma unroll
        for (int i = 0; i < RPW / 2; ++i) {
            int gp  = __builtin_amdgcn_ds_bpermute((i << 3) + vhi4, gidx);
            int off = (gp & ~127) + (f << 2);
            float g = *(const float*)(sum_bytes + off);
            g = (gp & 1) ? 0.f : g;
            float iv = __builtin_nontemporal_load(ip + i * 64);
            wptr[i * (2 * STRIDE)] = g + iv;
        }
    } else {
#pragma unroll
        for (int i = 0; i < RPW / 2; ++i) {
            int gp  = __builtin_amdgcn_ds_bpermute((i << 3) + vhi4, gidx);
            int off = (gp & ~127) + (f << 2);
            float g = *(const float*)(sum_bytes + off);
            g = (gp & 1) ? 0.f : g;
            int rr = wave_row0 + 2 * i + hi;
            if (rr >= NR) rr = NR - 1;
            float iv = init[(size_t)rr * FF + f];
            wptr[i * (2 * STRIDE)] = g + iv;
        }
    }

    // ---- stage 2: per-lane own row ----
    int p_raw = lane / DD;                     // 0..6
    int r_own = lane - p_raw * DD;
    const int pe   = (p_raw < PPW) ? p_raw : (PPW - 1);
    const int slot = pe * DD + r_own;          // <= 59
    float* rowp = &sROW[w][slot][0];

    f32x4 gi4[8];
#pragma unroll
    for (int q = 0; q < 8; ++q) gi4[q] = *(const f32x4*)(rowp + 4 * q);

    // zm of own row (lane<60: identity; shadows: fetch from slot lane)
    const float zm_o = __int_as_float(
        __builtin_amdgcn_ds_bpermute(slot << 2, __float_as_int(zm_s)));

    // dense: dot = raw @ W (W/bias/a uniform -> s_load; f32x2 -> v_pk_fma_f32)
    const f32x2* W2 = (const f32x2*)Wk;
    const f32x2* b2 = (const f32x2*)Wb;
    const f32x2* A2 = (const f32x2*)Ak;
    f32x2 T2[16];
#pragma unroll
    for (int i = 0; i < 16; ++i) T2[i] = (f32x2){0.f, 0.f};
#pragma unroll
    for (int ff = 0; ff < FF; ++ff) {
        float gf = gi4[ff >> 2][ff & 3];
        f32x2 gf2 = {gf, gf};
#pragma unroll
        for (int i = 0; i < 16; ++i) T2[i] = gf2 * W2[ff * 16 + i] + T2[i];
    }
    // T = relu(zm*dot + bias) * zm ; attn dot in-lane
    f32x2 z2 = {zm_o, zm_o};
    f32x2 acc2 = {0.f, 0.f};
#pragma unroll
    for (int i = 0; i < 16; ++i) {
        f32x2 v = z2 * T2[i] + b2[i];
        v.x = fmaxf(v.x, 0.f);
        v.y = fmaxf(v.y, 0.f);
        v = v * z2;
        T2[i] = v;
        acc2 = v * A2[i] + acc2;
    }
    const float aw = acc2.x + acc2.y - 1e7f * (1.f - zm_o);

    // softmax over the pair's 10 rows via ds_bpermute
    const int pe40 = pe * 40;
    float vals[DD];
    float mx = -INFINITY;
#pragma unroll
    for (int d = 0; d < DD; ++d) {
        vals[d] = __int_as_float(
            __builtin_amdgcn_ds_bpermute(pe40 + 4 * d, __float_as_int(aw)));
        mx = fmaxf(mx, vals[d]);
    }
    float den = 0.f;
#pragma unroll
    for (int d = 0; d < DD; ++d) den += __expf(vals[d] - mx);
    const float coef = __expf(aw - mx) / den;

    // writeback coef*T to own LDS row (guard: shadows would duplicate slots)
    if (p_raw < PPW) {
        f32x2 c2 = {coef, coef};
#pragma unroll
        for (int q = 0; q < 8; ++q) {
            f32x2 lo = T2[2 * q] * c2;
            f32x2 hv = T2[2 * q + 1] * c2;
            f32x4 vv;
            vv.x = lo.x; vv.y = lo.y; vv.z = hv.x; vv.w = hv.y;
            *(f32x4*)(rowp + 4 * q) = vv;
        }
    }

    // ---- epilogue: coalesced nt b128 stores ----
    int lim4;
    if (full) lim4 = RPW * 8;
    else {
        int nrows = NR - wave_row0;
        if (nrows < 0) nrows = 0;
        if (nrows > RPW) nrows = RPW;
        lim4 = nrows * 8;
    }
    f32x4* ob = (f32x4*)(out + (size_t)wave_row0 * FF);
#pragma unroll
    for (int k = 0; k < 8; ++k) {
        int m = lane + (k << 6);
        if (m < lim4) {
            const f32x4 v = *(const f32x4*)(wbase + (m >> 3) * STRIDE + ((m & 7) << 2));
            __builtin_nontemporal_store(v, ob + m);
        }
    }
}

extern "C" void kernel_launch(void* const* d_in, const int* in_sizes, int n_in,
                              void* d_out, int out_size, void* d_ws, size_t ws_size,
                              hipStream_t stream) {
    const float* inputs = (const float*)d_in[0];
    const float* init   = (const float*)d_in[1];
    const float* mask   = (const float*)d_in[2];
    const float* Wk     = (const float*)d_in[3];
    const float* Wb     = (const float*)d_in[4];
    const float* Ak     = (const float*)d_in[5];
    const int*   adj    = (const int*)d_in[6];
    const int*   mip    = (const int*)d_in[7];

    const int B   = 4;
    const int BVD = in_sizes[2];          // B*V*D
    const int V   = BVD / (B * DD);
    const int BV  = B * V;

    float* summed = (float*)d_ws;         // B*V*FF floats = 10.24 MB
    int n4 = BV * (FF / 4);
    hipLaunchKernelGGL(sum_d4_kernel, dim3((n4 + 255) / 256), dim3(256), 0, stream,
                       (const f32x4*)inputs, (f32x4*)summed, n4);
    const int ppb = NW * PPW;             // 12 pairs per block
    hipLaunchKernelGGL(gat_kernel, dim3((BV + ppb - 1) / ppb), dim3(NT), 0, stream,
                       summed, init, mask, Wk, Wb, Ak, adj, mip, (float*)d_out, B, V);
}

// Round 9
// 75.519 us; speedup vs baseline: 3.9736x; 1.0563x over previous
//
#include <hip/hip_runtime.h>
#include <cmath>

#define DD     10
#define FF     32
#define OUTN   32
#define PPW    6                 // pairs per wave (60 rows, lanes 60-63 shadow)
#define NW     2                 // waves per block
#define NT     (NW * 64)
#define RPW    (PPW * DD)        // 60 rows per wave
#define HR     (RPW / 2)         // 30 row-iterations per half-lane
#define STRIDE 36                // LDS row stride in floats (144 B, 16B-aligned)

typedef float f32x4 __attribute__((ext_vector_type(4)));
typedef float f32x2 __attribute__((ext_vector_type(2)));

// Kernel 1: summed[b,v,f] = sum_d inputs[b,v,d,f]  — at its roofline
__global__ __launch_bounds__(256) void sum_d4_kernel(
    const f32x4* __restrict__ in, f32x4* __restrict__ out, int n4) {
    int idx = blockIdx.x * 256 + threadIdx.x;
    if (idx >= n4) return;
    int f4 = idx & 7;
    int bv = idx >> 3;
    const f32x4* p = in + (size_t)bv * (DD * 8) + f4;
    f32x4 s = __builtin_nontemporal_load(p);
#pragma unroll
    for (int d = 1; d < DD; ++d) s += __builtin_nontemporal_load(p + d * 8);
    out[idx] = s;
}

// Kernel 2: coalesced staging (lane=f) -> LDS transpose -> per-lane-row dense.
// Stage 1 phased: all descriptors, then ALL loads in flight (VGPR-rich).
__global__ __launch_bounds__(NT, 2) void gat_kernel(
    const float* __restrict__ summed,
    const float* __restrict__ init,
    const float* __restrict__ mask,
    const float* __restrict__ Wk,
    const float* __restrict__ Wb,
    const float* __restrict__ Ak,
    const int* __restrict__ adj,
    const int* __restrict__ mask_index_p,
    float* __restrict__ out,
    int B, int V) {
    __shared__ float sROW[NW][RPW][STRIDE];   // 17280 B

    const int t    = threadIdx.x;
    const int lane = t & 63;
    const int w    = t >> 6;
    const int f    = lane & 31;
    const int hi   = lane >> 5;
    const int BV   = B * V;
    const int NR   = BV * DD;
    const int mask_index = *mask_index_p;

    const int wave_pair0 = (blockIdx.x * NW + w) * PPW;
    const int wave_row0  = wave_pair0 * DD;
    const bool full = (wave_pair0 + PPW) <= BV;

    // ---- per-slot prep (lane = slot): packed gather descriptor + zm ----
    int slot_row = wave_row0 + lane;
    if (slot_row >= NR) slot_row = NR - 1;
    const int   a_s  = adj[slot_row];
    const float zm_s = 1.f - mask[slot_row];
    int ac = a_s < 0 ? 0 : (a_s >= V ? V - 1 : a_s);          // JAX clamp
    int bv_s = slot_row / DD;
    int b_s  = (bv_s >= 2 * V) ? ((bv_s >= 3 * V) ? 3 : 2) : ((bv_s >= V) ? 1 : 0);
    const int gidx = ((b_s * V + ac) << 7) | ((a_s == mask_index) ? 1 : 0);

    // ---- stage 1: phased for max memory-level parallelism ----
    const int vhi4 = hi << 2;
    float* wbase = &sROW[w][0][0];
    float* wptr  = wbase + hi * STRIDE + f;
    const char* sum_bytes = (const char*)summed;

    int gp[HR];
#pragma unroll
    for (int i = 0; i < HR; ++i)
        gp[i] = __builtin_amdgcn_ds_bpermute((i << 3) + vhi4, gidx);

    float g[HR], iv[HR];
    if (full) {
        const float* ip = init + (size_t)wave_row0 * FF + lane;   // linear
#pragma unroll
        for (int i = 0; i < HR; ++i)
            g[i] = *(const float*)(sum_bytes + (gp[i] & ~127) + (f << 2));
#pragma unroll
        for (int i = 0; i < HR; ++i)
            iv[i] = __builtin_nontemporal_load(ip + i * 64);
    } else {
#pragma unroll
        for (int i = 0; i < HR; ++i)
            g[i] = *(const float*)(sum_bytes + (gp[i] & ~127) + (f << 2));
#pragma unroll
        for (int i = 0; i < HR; ++i) {
            int rr = wave_row0 + 2 * i + hi;
            if (rr >= NR) rr = NR - 1;
            iv[i] = init[(size_t)rr * FF + f];
        }
    }
#pragma unroll
    for (int i = 0; i < HR; ++i)
        wptr[i * (2 * STRIDE)] = ((gp[i] & 1) ? 0.f : g[i]) + iv[i];

    // ---- stage 2: per-lane own row ----
    int p_raw = lane / DD;                     // 0..6
    int r_own = lane - p_raw * DD;
    const int pe   = (p_raw < PPW) ? p_raw : (PPW - 1);
    const int slot = pe * DD + r_own;          // <= 59
    float* rowp = &sROW[w][slot][0];

    f32x4 gi4[8];
#pragma unroll
    for (int q = 0; q < 8; ++q) gi4[q] = *(const f32x4*)(rowp + 4 * q);

    // zm of own row (lane<60: identity; shadows: fetch from slot lane)
    const float zm_o = __int_as_float(
        __builtin_amdgcn_ds_bpermute(slot << 2, __float_as_int(zm_s)));

    // dense: dot = raw @ W (W/bias/a uniform -> s_load; f32x2 -> v_pk_fma_f32)
    const f32x2* W2 = (const f32x2*)Wk;
    const f32x2* b2 = (const f32x2*)Wb;
    const f32x2* A2 = (const f32x2*)Ak;
    f32x2 T2[16];
#pragma unroll
    for (int i = 0; i < 16; ++i) T2[i] = (f32x2){0.f, 0.f};
#pragma unroll
    for (int ff = 0; ff < FF; ++ff) {
        float gf = gi4[ff >> 2][ff & 3];
        f32x2 gf2 = {gf, gf};
#pragma unroll
        for (int i = 0; i < 16; ++i) T2[i] = gf2 * W2[ff * 16 + i] + T2[i];
    }
    // T = relu(zm*dot + bias) * zm ; attn dot in-lane
    f32x2 z2 = {zm_o, zm_o};
    f32x2 acc2 = {0.f, 0.f};
#pragma unroll
    for (int i = 0; i < 16; ++i) {
        f32x2 v = z2 * T2[i] + b2[i];
        v.x = fmaxf(v.x, 0.f);
        v.y = fmaxf(v.y, 0.f);
        v = v * z2;
        T2[i] = v;
        acc2 = v * A2[i] + acc2;
    }
    const float aw = acc2.x + acc2.y - 1e7f * (1.f - zm_o);

    // softmax over the pair's 10 rows via ds_bpermute
    const int pe40 = pe * 40;
    float vals[DD];
    float mx = -INFINITY;
#pragma unroll
    for (int d = 0; d < DD; ++d) {
        vals[d] = __int_as_float(
            __builtin_amdgcn_ds_bpermute(pe40 + 4 * d, __float_as_int(aw)));
        mx = fmaxf(mx, vals[d]);
    }
    float den = 0.f;
#pragma unroll
    for (int d = 0; d < DD; ++d) den += __expf(vals[d] - mx);
    const float coef = __expf(aw - mx) / den;

    // writeback coef*T to own LDS row (guard: shadows would duplicate slots)
    if (p_raw < PPW) {
        f32x2 c2 = {coef, coef};
#pragma unroll
        for (int q = 0; q < 8; ++q) {
            f32x2 lo = T2[2 * q] * c2;
            f32x2 hv = T2[2 * q + 1] * c2;
            f32x4 vv;
            vv.x = lo.x; vv.y = lo.y; vv.z = hv.x; vv.w = hv.y;
            *(f32x4*)(rowp + 4 * q) = vv;
        }
    }

    // ---- epilogue: coalesced nt b128 stores ----
    int lim4;
    if (full) lim4 = RPW * 8;
    else {
        int nrows = NR - wave_row0;
        if (nrows < 0) nrows = 0;
        if (nrows > RPW) nrows = RPW;
        lim4 = nrows * 8;
    }
    f32x4* ob = (f32x4*)(out + (size_t)wave_row0 * FF);
#pragma unroll
    for (int k = 0; k < 8; ++k) {
        int m = lane + (k << 6);
        if (m < lim4) {
            const f32x4 v = *(const f32x4*)(wbase + (m >> 3) * STRIDE + ((m & 7) << 2));
            __builtin_nontemporal_store(v, ob + m);
        }
    }
}

extern "C" void kernel_launch(void* const* d_in, const int* in_sizes, int n_in,
                              void* d_out, int out_size, void* d_ws, size_t ws_size,
                              hipStream_t stream) {
    const float* inputs = (const float*)d_in[0];
    const float* init   = (const float*)d_in[1];
    const float* mask   = (const float*)d_in[2];
    const float* Wk     = (const float*)d_in[3];
    const float* Wb     = (const float*)d_in[4];
    const float* Ak     = (const float*)d_in[5];
    const int*   adj    = (const int*)d_in[6];
    const int*   mip    = (const int*)d_in[7];

    const int B   = 4;
    const int BVD = in_sizes[2];          // B*V*D
    const int V   = BVD / (B * DD);
    const int BV  = B * V;

    float* summed = (float*)d_ws;         // B*V*FF floats = 10.24 MB
    int n4 = BV * (FF / 4);
    hipLaunchKernelGGL(sum_d4_kernel, dim3((n4 + 255) / 256), dim3(256), 0, stream,
                       (const f32x4*)inputs, (f32x4*)summed, n4);
    const int ppb = NW * PPW;             // 12 pairs per block
    hipLaunchKernelGGL(gat_kernel, dim3((BV + ppb - 1) / ppb), dim3(NT), 0, stream,
                       summed, init, mask, Wk, Wb, Ak, adj, mip, (float*)d_out, B, V);
}